// Round 6
// baseline (650.761 us; speedup 1.0000x reference)
//
#include <hip/hip_runtime.h>
#include <math.h>

#define Bb 2
#define Nn 32768
#define Cc 128
#define Ff 128
#define LL 4
#define SKN 128
#define PS 16448   // Spart plane stride (floats): 16384+64 breaks power-of-2 channel aliasing
#define TWOPI 6.283185307179586f

typedef __attribute__((ext_vector_type(8))) short short8;
typedef __attribute__((ext_vector_type(4))) float float4v;
typedef __attribute__((ext_vector_type(2))) unsigned int uint2v;
typedef unsigned short ushort_t;
typedef unsigned int uint_t;

union frag_cast { short8 s; uint_t u[4]; };
union vec8 { float4v v[2]; float s[8]; };

__device__ inline uint_t asu(float f) { union { float f; uint_t u; } x; x.f = f; return x.u; }
__device__ inline float asf(uint_t u) { union { uint_t u; float f; } x; x.u = u; return x.f; }
// pack: low16 = bf16-trunc(v0), high16 = bf16-trunc(v1)
__device__ inline uint_t pack_hi(float v0, float v1) { return (asu(v0) >> 16) | (asu(v1) & 0xffff0000u); }
// exact residual after bf16 truncation
__device__ inline float resid(float v) { return v - asf(asu(v) & 0xffff0000u); }

// ---------------- prep: transpose x,y -> [b][d][n] planes
__global__ __launch_bounds__(256) void prep_xt(const float* __restrict__ x,
                                               const float* __restrict__ y,
                                               float* __restrict__ xT,
                                               float* __restrict__ yT) {
    int i = blockIdx.x * 256 + threadIdx.x;        // b*Nn + n
    int b = i >> 15, n = i & 32767;
    const float* xp = x + (size_t)i * 3;
    const float* yp = y + (size_t)i * 3;
    size_t base = ((size_t)(b * 3) << 15) + n;
    xT[base] = xp[0]; xT[base + (1 << 15)] = xp[1]; xT[base + (2 << 15)] = xp[2];
    yT[base] = yp[0]; yT[base + (1 << 15)] = yp[1]; yT[base + (2 << 15)] = yp[2];
}

// ---------------- in projection -> packed bf16 hi/lo planes hfTh/hfTl[b][c][n-pair]
__global__ __launch_bounds__(256) void in_proj(const float* __restrict__ a,
                                               const float* __restrict__ w,
                                               const float* __restrict__ bias,
                                               uint_t* __restrict__ hfTh,
                                               uint_t* __restrict__ hfTl) {
    int idx = blockIdx.x * 256 + threadIdx.x;      // b*C*(N/2) + c*(N/2) + np
    int np = idx & 16383;
    int c = (idx >> 14) & 127;
    int b = idx >> 21;
    int n = np * 2;
    const float* ap = a + (((size_t)(b << 15)) + n) * 4;
    float s0 = bias[c], s1 = s0;
#pragma unroll
    for (int i = 0; i < 4; ++i) { s0 += ap[i] * w[i * Cc + c]; s1 += ap[4 + i] * w[i * Cc + c]; }
    hfTh[idx] = pack_hi(s0, s1);
    hfTl[idx] = pack_hi(resid(s0), resid(s1));
}

// ---------------- forward transform: barrier-free, zero-LDS.
// Block = 64c x 64f x 2h; 4 waves = (h 2) x (wn 2 f-quarters); wave tile 64c x 32f.
// Trig computed once per block (waves own disjoint f); A pre-packed -> zero staging VALU.
__global__ __launch_bounds__(256, 4) void fwd_bf(const uint_t* __restrict__ hfTh,
                                                 const uint_t* __restrict__ hfTl,
                                                 const float* __restrict__ xT,
                                                 const float* __restrict__ freqs,
                                                 float* __restrict__ Spart) {
    const int sk = blockIdx.x;
    const int ct = blockIdx.y & 1, ft = blockIdx.y >> 1;
    const int b = blockIdx.z;
    const int n0 = sk * (Nn / SKN);                // 256-point chunk
    const int tid = threadIdx.x, lane = tid & 63, wave = tid >> 6;
    const int h = wave >> 1, wn = wave & 1;
    const int fr = lane & 15, kg = lane >> 4;

    // per-lane fixed frequencies (pre-scaled by 2pi) for the 2 B-frag columns
    float kx[2], ky[2], kz[2];
#pragma unroll
    for (int ni = 0; ni < 2; ++ni) {
        int f = ft * 64 + wn * 32 + ni * 16 + fr;
        kx[ni] = TWOPI * freqs[f * 3 + 0];
        ky[ni] = TWOPI * freqs[f * 3 + 1];
        kz[ni] = TWOPI * freqs[f * 3 + 2];
    }

    const float* xb = xT + ((size_t)(b * 3) << 15);
    const int crow0 = b * 128 + ct * 64;

    float4v acc[4][2];
#pragma unroll
    for (int mi = 0; mi < 4; ++mi)
#pragma unroll
        for (int ni = 0; ni < 2; ++ni) acc[mi][ni] = (float4v){0.f, 0.f, 0.f, 0.f};

    for (int kt = 0; kt < Nn / SKN; kt += 32) {
        const int nbase = n0 + kt + kg * 8;        // this lane's 8 k-points
        vec8 X0, X1, X2;
        X0.v[0] = *(const float4v*)(xb + nbase);
        X0.v[1] = *(const float4v*)(xb + nbase + 4);
        X1.v[0] = *(const float4v*)(xb + (1 << 15) + nbase);
        X1.v[1] = *(const float4v*)(xb + (1 << 15) + nbase + 4);
        X2.v[0] = *(const float4v*)(xb + (2 << 15) + nbase);
        X2.v[1] = *(const float4v*)(xb + (2 << 15) + nbase + 4);

        frag_cast bh[2], bl[2];
#pragma unroll
        for (int ni = 0; ni < 2; ++ni)
#pragma unroll
            for (int q = 0; q < 4; ++q) {
                float a0 = X0.s[2 * q] * kx[ni] + X1.s[2 * q] * ky[ni] + X2.s[2 * q] * kz[ni];
                float a1 = X0.s[2 * q + 1] * kx[ni] + X1.s[2 * q + 1] * ky[ni] + X2.s[2 * q + 1] * kz[ni];
                float v0 = h ? __sinf(a0) : __cosf(a0);
                float v1 = h ? __sinf(a1) : __cosf(a1);
                bh[ni].u[q] = pack_hi(v0, v1);
                bl[ni].u[q] = pack_hi(resid(v0), resid(v1));
            }

#pragma unroll
        for (int mi = 0; mi < 4; ++mi) {
            const size_t rowoff = ((size_t)(crow0 + mi * 16 + fr) << 14) + (nbase >> 1);
            frag_cast ah, al;
            ah.s = *(const short8*)(hfTh + rowoff);
            al.s = *(const short8*)(hfTl + rowoff);
#pragma unroll
            for (int ni = 0; ni < 2; ++ni) {
                acc[mi][ni] = __builtin_amdgcn_mfma_f32_16x16x32_bf16(ah.s, bh[ni].s, acc[mi][ni], 0, 0, 0);
                acc[mi][ni] = __builtin_amdgcn_mfma_f32_16x16x32_bf16(ah.s, bl[ni].s, acc[mi][ni], 0, 0, 0);
                acc[mi][ni] = __builtin_amdgcn_mfma_f32_16x16x32_bf16(al.s, bh[ni].s, acc[mi][ni], 0, 0, 0);
            }
        }
    }

    float* op = Spart + (size_t)((b * 2 + h) * SKN + sk) * PS;
#pragma unroll
    for (int mi = 0; mi < 4; ++mi)
#pragma unroll
        for (int ni = 0; ni < 2; ++ni)
#pragma unroll
            for (int r = 0; r < 4; ++r) {
                int c = ct * 64 + mi * 16 + kg * 4 + r;
                int f = ft * 64 + wn * 32 + ni * 16 + fr;
                op[c * 128 + f] = acc[mi][ni][r];
            }
}

// ---------------- reduce split-K partials, two-stage in-block (1024 blocks)
__global__ __launch_bounds__(256) void reduce_kernel(const float* __restrict__ Spart,
                                                     float* __restrict__ S) {
    __shared__ float red[4][64];
    const int chunk = blockIdx.x, bh = blockIdx.y;
    const int tid = threadIdx.x;
    const int cfl = tid & 63, q = tid >> 6;
    const float* p = Spart + (size_t)bh * SKN * PS + (size_t)(q * 32) * PS + chunk * 64 + cfl;
    float s = 0.0f;
#pragma unroll 8
    for (int k = 0; k < 32; ++k) s += p[(size_t)k * PS];
    red[q][cfl] = s;
    __syncthreads();
    if (tid < 64) {
        float t = red[0][tid] + red[1][tid] + red[2][tid] + red[3][tid];
        S[bh * 16384 + chunk * 64 + tid] = t;
    }
}

// ---------------- channel mixing -> packed bf16 hi/lo G planes (512 blocks, W read once)
__global__ __launch_bounds__(256) void mix_kernel(const float* __restrict__ S,
                                                  const float* __restrict__ Wre,
                                                  const float* __restrict__ Wim,
                                                  uint_t* __restrict__ Gh,
                                                  uint_t* __restrict__ Gl) {
    __shared__ float Stile[4][128][16];            // [b*2+h][c][f-local], 32 KB
    const int ot = blockIdx.x;                     // 64 tiles of 2 o
    const int ft = blockIdx.y;                     // 8 tiles of 16 f
    const int tid = threadIdx.x;
    const int fl = tid & 15, ol = (tid >> 4) & 1, cg = tid >> 5;   // cg: 8-way c-split
    const int o = ot * 2 + ol, f0 = ft * 16;

    for (int i = tid; i < 8192; i += 256) {
        int bh = i >> 11, c = (i >> 4) & 127, ff = i & 15;
        Stile[bh][c][ff] = S[(size_t)bh * 16384 + c * 128 + f0 + ff];
    }
    __syncthreads();

    float g0 = 0.f, g1 = 0.f, g2 = 0.f, g3 = 0.f;  // gre_b0, gmi_b0, gre_b1, gmi_b1
#pragma unroll 4
    for (int c = cg * 16; c < cg * 16 + 16; ++c) {
        float wr = Wre[((size_t)(c * 128 + o)) * 128 + f0 + fl];
        float wi = Wim[((size_t)(c * 128 + o)) * 128 + f0 + fl];
        float sc0 = Stile[0][c][fl], ss0 = Stile[1][c][fl];
        float sc1 = Stile[2][c][fl], ss1 = Stile[3][c][fl];
        g0 += sc0 * wr + ss0 * wi;  g1 += ss0 * wr - sc0 * wi;
        g2 += sc1 * wr + ss1 * wi;  g3 += ss1 * wr - sc1 * wi;
    }
    __syncthreads();
    float4v* rp = (float4v*)Stile;                 // reuse LDS: 8 cg x 32 (ol,fl)
    rp[cg * 32 + ol * 16 + fl] = (float4v){g0, g1, g2, g3};
    __syncthreads();
    if (tid < 32) {
        int tol = tid >> 4, tfl = tid & 15;
        float4v r = rp[tid];
#pragma unroll
        for (int j = 1; j < 8; ++j) r += rp[j * 32 + tid];
        const float invN = 1.0f / (float)Nn;
        float gre0 = r[0] * invN, gmi0 = r[1] * invN;
        float gre1 = r[2] * invN, gmi1 = r[3] * invN;
        int oo = ot * 2 + tol;
        Gh[(0 * 128 + oo) * 128 + f0 + tfl] = pack_hi(gre0, gmi0);
        Gl[(0 * 128 + oo) * 128 + f0 + tfl] = pack_hi(resid(gre0), resid(gmi0));
        Gh[(1 * 128 + oo) * 128 + f0 + tfl] = pack_hi(gre1, gmi1);
        Gl[(1 * 128 + oo) * 128 + f0 + tfl] = pack_hi(resid(gre1), resid(gmi1));
    }
}

// ---------------- inverse evaluation + gelu: n-tile 32, grid 2048, small wave tile (16n x 64o)
// k = 2f+h: even k -> cos*Gre, odd k -> sin*Gmi. Output packed into hfTh/hfTl.
__global__ __launch_bounds__(256, 6) void inv_bf(const uint_t* __restrict__ Gh,
                                                 const uint_t* __restrict__ Gl,
                                                 const float* __restrict__ ptsT,
                                                 const float* __restrict__ freqs,
                                                 uint_t* __restrict__ hfTh,
                                                 uint_t* __restrict__ hfTl) {
    __shared__ __align__(16) float kxs[128], kys[128], kzs[128];
    const int nt = blockIdx.x, b = blockIdx.y;
    const int n0 = nt * 32;
    const int tid = threadIdx.x, lane = tid & 63, wave = tid >> 6;
    const int wm = wave & 1, wn = wave >> 1;       // 2 n-halves x 2 o-halves
    const int fr = lane & 15, kg = lane >> 4;

    if (tid < 128) {
        kxs[tid] = TWOPI * freqs[tid * 3 + 0];
        kys[tid] = TWOPI * freqs[tid * 3 + 1];
        kzs[tid] = TWOPI * freqs[tid * 3 + 2];
    }

    const float* pb = ptsT + ((size_t)(b * 3) << 15);
    const int nrow = n0 + wm * 16 + fr;
    float px = pb[nrow], py = pb[(1 << 15) + nrow], pz = pb[(2 << 15) + nrow];
    __syncthreads();

    float4v acc[4];
#pragma unroll
    for (int ni = 0; ni < 4; ++ni) acc[ni] = (float4v){0.f, 0.f, 0.f, 0.f};

#pragma unroll
    for (int kt = 0; kt < 8; ++kt) {
        const int fbase = kt * 16 + kg * 4;
        float4v kxv = *(const float4v*)&kxs[fbase];
        float4v kyv = *(const float4v*)&kys[fbase];
        float4v kzv = *(const float4v*)&kzs[fbase];

        frag_cast bh[4], bl[4];
#pragma unroll
        for (int ni = 0; ni < 4; ++ni) {
            size_t gi = ((size_t)(b * 128 + wn * 64 + ni * 16 + fr)) * 128 + fbase;
            bh[ni].s = *(const short8*)(Gh + gi);
            bl[ni].s = *(const short8*)(Gl + gi);
        }
        frag_cast ah, al;
#pragma unroll
        for (int q = 0; q < 4; ++q) {
            float ang = px * kxv[q] + py * kyv[q] + pz * kzv[q];
            float cv = __cosf(ang), sv = __sinf(ang);
            ah.u[q] = pack_hi(cv, sv);
            al.u[q] = pack_hi(resid(cv), resid(sv));
        }
#pragma unroll
        for (int ni = 0; ni < 4; ++ni) {
            acc[ni] = __builtin_amdgcn_mfma_f32_16x16x32_bf16(ah.s, bh[ni].s, acc[ni], 0, 0, 0);
            acc[ni] = __builtin_amdgcn_mfma_f32_16x16x32_bf16(ah.s, bl[ni].s, acc[ni], 0, 0, 0);
            acc[ni] = __builtin_amdgcn_mfma_f32_16x16x32_bf16(al.s, bh[ni].s, acc[ni], 0, 0, 0);
        }
    }

    // epilogue: gelu (tanh approx via expf) + packed bf16 hi/lo store
#pragma unroll
    for (int ni = 0; ni < 4; ++ni) {
        float g[4];
#pragma unroll
        for (int r = 0; r < 4; ++r) {
            float v = acc[ni][r];
            float u2 = 1.5957691216057308f * (v + 0.044715f * v * v * v);
            float t = 1.0f - 2.0f / (1.0f + __expf(u2));
            g[r] = 0.5f * v * (1.0f + t);
        }
        int o = wn * 64 + ni * 16 + fr;
        int nb = n0 + wm * 16 + kg * 4;
        size_t di = ((size_t)(b * 128 + o) << 14) + (nb >> 1);
        uint2v hv = { pack_hi(g[0], g[1]), pack_hi(g[2], g[3]) };
        uint2v lv = { pack_hi(resid(g[0]), resid(g[1])), pack_hi(resid(g[2]), resid(g[3])) };
        *(uint2v*)(hfTh + di) = hv;
        *(uint2v*)(hfTl + di) = lv;
    }
}

// ---------------- out projection (reads packed hfT planes)
__global__ __launch_bounds__(256) void out_proj(const uint_t* __restrict__ hfTh,
                                                const uint_t* __restrict__ hfTl,
                                                const float* __restrict__ w,
                                                const float* __restrict__ bias,
                                                float* __restrict__ u) {
    int i = blockIdx.x * 256 + threadIdx.x;        // b*(N/2) + np
    int b = i >> 14, np = i & 16383;
    const uint_t* hp = hfTh + ((size_t)(b * 128) << 14) + np;
    const uint_t* lp = hfTl + ((size_t)(b * 128) << 14) + np;
    float s0a = bias[0], s1a = bias[1], s0b = bias[0], s1b = bias[1];
#pragma unroll 4
    for (int c = 0; c < 128; ++c) {
        uint_t hv = hp[(size_t)c << 14], lv = lp[(size_t)c << 14];
        float v0 = asf(hv << 16) + asf(lv << 16);
        float v1 = asf(hv & 0xffff0000u) + asf(lv & 0xffff0000u);
        float w0 = w[c * 2 + 0], w1 = w[c * 2 + 1];
        s0a += v0 * w0; s1a += v0 * w1;
        s0b += v1 * w0; s1b += v1 * w1;
    }
    float4v o4 = {s0a, s1a, s0b, s1b};
    *(float4v*)(u + ((size_t)(b << 15) + np * 2) * 2) = o4;
}

extern "C" void kernel_launch(void* const* d_in, const int* in_sizes, int n_in,
                              void* d_out, int out_size, void* d_ws, size_t ws_size,
                              hipStream_t stream) {
    const float* a        = (const float*)d_in[0];
    const float* x        = (const float*)d_in[1];
    const float* y        = (const float*)d_in[2];
    const float* fc_in_w  = (const float*)d_in[3];
    const float* fc_in_b  = (const float*)d_in[4];
    const float* freqs    = (const float*)d_in[5];
    const float* w_real   = (const float*)d_in[6];
    const float* w_imag   = (const float*)d_in[7];
    const float* fc_out_w = (const float*)d_in[8];
    const float* fc_out_b = (const float*)d_in[9];
    float* out = (float*)d_out;

    uint_t* ws    = (uint_t*)d_ws;
    uint_t* hfTh  = ws;                                        // B*C*N/2 = 4,194,304 dwords
    uint_t* hfTl  = hfTh + (size_t)Bb * Cc * Nn / 2;           // 4,194,304
    float*  Spart = (float*)(hfTl + (size_t)Bb * Cc * Nn / 2); // B*2*SKN*PS = 8,421,376 floats
    float*  S     = Spart + (size_t)Bb * 2 * SKN * PS;         // 65,536
    uint_t* Gh    = (uint_t*)(S + (size_t)Bb * 2 * Cc * Ff);   // 32,768
    uint_t* Gl    = Gh + (size_t)Bb * Cc * Ff;                 // 32,768
    float*  xT    = (float*)(Gl + (size_t)Bb * Cc * Ff);       // 196,608 floats
    float*  yT    = xT + (size_t)Bb * 3 * Nn;                  // 196,608

    prep_xt<<<(Bb * Nn) / 256, 256, 0, stream>>>(x, y, xT, yT);
    in_proj<<<(Bb * Cc * Nn / 2) / 256, 256, 0, stream>>>(a, fc_in_w, fc_in_b, hfTh, hfTl);

    for (int l = 0; l < LL; ++l) {
        const float* k   = freqs  + (size_t)l * Ff * 3;
        const float* Wre = w_real + (size_t)l * Cc * Cc * Ff;
        const float* Wim = w_imag + (size_t)l * Cc * Cc * Ff;
        const float* pT  = (l < LL - 1) ? xT : yT;

        fwd_bf<<<dim3(SKN, 4, Bb), 256, 0, stream>>>(hfTh, hfTl, xT, k, Spart);
        reduce_kernel<<<dim3(256, 4), 256, 0, stream>>>(Spart, S);
        mix_kernel<<<dim3(64, 8), 256, 0, stream>>>(S, Wre, Wim, Gh, Gl);
        inv_bf<<<dim3(Nn / 32, Bb), 256, 0, stream>>>(Gh, Gl, pT, k, hfTh, hfTl);
    }

    out_proj<<<(Bb * Nn / 2) / 256, 256, 0, stream>>>(hfTh, hfTl, fc_out_w, fc_out_b, out);
}

// Round 7
// 503.541 us; speedup vs baseline: 1.2924x; 1.2924x over previous
//
#include <hip/hip_runtime.h>
#include <math.h>

#define Bb 2
#define Nn 32768
#define Cc 128
#define Ff 128
#define LL 4
#define SKN 128
#define PS 16448   // Spart plane stride (floats): breaks power-of-2 channel aliasing
#define TWOPI 6.283185307179586f

typedef __attribute__((ext_vector_type(8))) short short8;
typedef __attribute__((ext_vector_type(4))) float float4v;
typedef __attribute__((ext_vector_type(2))) unsigned int uint2v;
typedef unsigned short ushort_t;
typedef unsigned int uint_t;

union frag_cast { short8 s; uint_t u[4]; };
union vec8 { float4v v[2]; float s[8]; };

__device__ inline uint_t asu(float f) { union { float f; uint_t u; } x; x.f = f; return x.u; }
__device__ inline float asf(uint_t u) { union { uint_t u; float f; } x; x.u = u; return x.f; }
// pack: low16 = bf16-trunc(v0), high16 = bf16-trunc(v1)
__device__ inline uint_t pack_hi(float v0, float v1) { return (asu(v0) >> 16) | (asu(v1) & 0xffff0000u); }
// exact residual after bf16 truncation
__device__ inline float resid(float v) { return v - asf(asu(v) & 0xffff0000u); }

// ---------------- prep: transpose x,y -> [b][d][n] planes
__global__ __launch_bounds__(256) void prep_xt(const float* __restrict__ x,
                                               const float* __restrict__ y,
                                               float* __restrict__ xT,
                                               float* __restrict__ yT) {
    int i = blockIdx.x * 256 + threadIdx.x;        // b*Nn + n
    int b = i >> 15, n = i & 32767;
    const float* xp = x + (size_t)i * 3;
    const float* yp = y + (size_t)i * 3;
    size_t base = ((size_t)(b * 3) << 15) + n;
    xT[base] = xp[0]; xT[base + (1 << 15)] = xp[1]; xT[base + (2 << 15)] = xp[2];
    yT[base] = yp[0]; yT[base + (1 << 15)] = yp[1]; yT[base + (2 << 15)] = yp[2];
}

// ---------------- in projection -> packed bf16 hi/lo planes hfTh/hfTl[b][c][n-pair]
__global__ __launch_bounds__(256) void in_proj(const float* __restrict__ a,
                                               const float* __restrict__ w,
                                               const float* __restrict__ bias,
                                               uint_t* __restrict__ hfTh,
                                               uint_t* __restrict__ hfTl) {
    int idx = blockIdx.x * 256 + threadIdx.x;      // b*C*(N/2) + c*(N/2) + np
    int np = idx & 16383;
    int c = (idx >> 14) & 127;
    int b = idx >> 21;
    int n = np * 2;
    const float* ap = a + (((size_t)(b << 15)) + n) * 4;
    float s0 = bias[c], s1 = s0;
#pragma unroll
    for (int i = 0; i < 4; ++i) { s0 += ap[i] * w[i * Cc + c]; s1 += ap[4 + i] * w[i * Cc + c]; }
    hfTh[idx] = pack_hi(s0, s1);
    hfTl[idx] = pack_hi(resid(s0), resid(s1));
}

// ---------------- forward transform: barrier-free, zero-LDS, explicit A/X double-buffer.
// Block 256 thr = 4 waves (h 2 x wn 2); wave tile 64c x 32f; grid (SKN, ct2*ft2, Bb).
__global__ __launch_bounds__(256, 3) void fwd_bf(const uint_t* __restrict__ hfTh,
                                                 const uint_t* __restrict__ hfTl,
                                                 const float* __restrict__ xT,
                                                 const float* __restrict__ freqs,
                                                 float* __restrict__ Spart) {
    const int sk = blockIdx.x;
    const int ct = blockIdx.y & 1, ft = blockIdx.y >> 1;
    const int b = blockIdx.z;
    const int n0 = sk * (Nn / SKN);                // 256-point chunk
    const int tid = threadIdx.x, lane = tid & 63, wave = tid >> 6;
    const int h = wave & 1, wn = wave >> 1;
    const int fr = lane & 15, kg = lane >> 4;

    // per-lane fixed frequencies (pre-scaled by 2pi) for the 2 B-frag columns
    float kx[2], ky[2], kz[2];
#pragma unroll
    for (int ni = 0; ni < 2; ++ni) {
        int f = ft * 64 + wn * 32 + ni * 16 + fr;
        kx[ni] = TWOPI * freqs[f * 3 + 0];
        ky[ni] = TWOPI * freqs[f * 3 + 1];
        kz[ni] = TWOPI * freqs[f * 3 + 2];
    }

    const float* xb = xT + ((size_t)(b * 3) << 15);
    const int crow0 = b * 128 + ct * 64;

    float4v acc[4][2];
#pragma unroll
    for (int mi = 0; mi < 4; ++mi)
#pragma unroll
        for (int ni = 0; ni < 2; ++ni) acc[mi][ni] = (float4v){0.f, 0.f, 0.f, 0.f};

    vec8 X0[2], X1[2], X2[2];
    frag_cast ahb[2][4], alb[2][4];

    // preload buffer 0 (kt = 0)
    {
        const int nbase = n0 + kg * 8;
        X0[0].v[0] = *(const float4v*)(xb + nbase);
        X0[0].v[1] = *(const float4v*)(xb + nbase + 4);
        X1[0].v[0] = *(const float4v*)(xb + (1 << 15) + nbase);
        X1[0].v[1] = *(const float4v*)(xb + (1 << 15) + nbase + 4);
        X2[0].v[0] = *(const float4v*)(xb + (2 << 15) + nbase);
        X2[0].v[1] = *(const float4v*)(xb + (2 << 15) + nbase + 4);
#pragma unroll
        for (int mi = 0; mi < 4; ++mi) {
            const size_t rowoff = ((size_t)(crow0 + mi * 16 + fr) << 14) + (nbase >> 1);
            ahb[0][mi].s = *(const short8*)(hfTh + rowoff);
            alb[0][mi].s = *(const short8*)(hfTl + rowoff);
        }
    }

#pragma unroll
    for (int kt = 0; kt < 8; ++kt) {
        const int cur = kt & 1, nxt = cur ^ 1;
        if (kt < 7) {                              // issue next-tile loads first
            const int nbase2 = n0 + (kt + 1) * 32 + kg * 8;
            X0[nxt].v[0] = *(const float4v*)(xb + nbase2);
            X0[nxt].v[1] = *(const float4v*)(xb + nbase2 + 4);
            X1[nxt].v[0] = *(const float4v*)(xb + (1 << 15) + nbase2);
            X1[nxt].v[1] = *(const float4v*)(xb + (1 << 15) + nbase2 + 4);
            X2[nxt].v[0] = *(const float4v*)(xb + (2 << 15) + nbase2);
            X2[nxt].v[1] = *(const float4v*)(xb + (2 << 15) + nbase2 + 4);
#pragma unroll
            for (int mi = 0; mi < 4; ++mi) {
                const size_t rowoff = ((size_t)(crow0 + mi * 16 + fr) << 14) + (nbase2 >> 1);
                ahb[nxt][mi].s = *(const short8*)(hfTh + rowoff);
                alb[nxt][mi].s = *(const short8*)(hfTl + rowoff);
            }
        }
        // trig B-frags from current X
        frag_cast bh[2], bl[2];
#pragma unroll
        for (int ni = 0; ni < 2; ++ni)
#pragma unroll
            for (int q = 0; q < 4; ++q) {
                float a0 = X0[cur].s[2 * q] * kx[ni] + X1[cur].s[2 * q] * ky[ni] + X2[cur].s[2 * q] * kz[ni];
                float a1 = X0[cur].s[2 * q + 1] * kx[ni] + X1[cur].s[2 * q + 1] * ky[ni] + X2[cur].s[2 * q + 1] * kz[ni];
                float v0 = h ? __sinf(a0) : __cosf(a0);
                float v1 = h ? __sinf(a1) : __cosf(a1);
                bh[ni].u[q] = pack_hi(v0, v1);
                bl[ni].u[q] = pack_hi(resid(v0), resid(v1));
            }
#pragma unroll
        for (int mi = 0; mi < 4; ++mi)
#pragma unroll
            for (int ni = 0; ni < 2; ++ni) {
                acc[mi][ni] = __builtin_amdgcn_mfma_f32_16x16x32_bf16(ahb[cur][mi].s, bh[ni].s, acc[mi][ni], 0, 0, 0);
                acc[mi][ni] = __builtin_amdgcn_mfma_f32_16x16x32_bf16(ahb[cur][mi].s, bl[ni].s, acc[mi][ni], 0, 0, 0);
                acc[mi][ni] = __builtin_amdgcn_mfma_f32_16x16x32_bf16(alb[cur][mi].s, bh[ni].s, acc[mi][ni], 0, 0, 0);
            }
    }

    float* op = Spart + (size_t)((b * 2 + h) * SKN + sk) * PS;
#pragma unroll
    for (int mi = 0; mi < 4; ++mi)
#pragma unroll
        for (int ni = 0; ni < 2; ++ni)
#pragma unroll
            for (int r = 0; r < 4; ++r) {
                int c = ct * 64 + mi * 16 + kg * 4 + r;
                int f = ft * 64 + wn * 32 + ni * 16 + fr;
                op[c * 128 + f] = acc[mi][ni][r];
            }
}

// ---------------- reduce split-K partials, two-stage in-block (1024 blocks)
__global__ __launch_bounds__(256) void reduce_kernel(const float* __restrict__ Spart,
                                                     float* __restrict__ S) {
    __shared__ float red[4][64];
    const int chunk = blockIdx.x, bh = blockIdx.y;
    const int tid = threadIdx.x;
    const int cfl = tid & 63, q = tid >> 6;
    const float* p = Spart + (size_t)bh * SKN * PS + (size_t)(q * 32) * PS + chunk * 64 + cfl;
    float s = 0.0f;
#pragma unroll 8
    for (int k = 0; k < 32; ++k) s += p[(size_t)k * PS];
    red[q][cfl] = s;
    __syncthreads();
    if (tid < 64) {
        float t = red[0][tid] + red[1][tid] + red[2][tid] + red[3][tid];
        S[bh * 16384 + chunk * 64 + tid] = t;
    }
}

// ---------------- channel mixing -> packed bf16 hi/lo G planes (512 blocks, W read once)
__global__ __launch_bounds__(256) void mix_kernel(const float* __restrict__ S,
                                                  const float* __restrict__ Wre,
                                                  const float* __restrict__ Wim,
                                                  uint_t* __restrict__ Gh,
                                                  uint_t* __restrict__ Gl) {
    __shared__ float Stile[4][128][16];            // [b*2+h][c][f-local], 32 KB
    const int ot = blockIdx.x;                     // 64 tiles of 2 o
    const int ft = blockIdx.y;                     // 8 tiles of 16 f
    const int tid = threadIdx.x;
    const int fl = tid & 15, ol = (tid >> 4) & 1, cg = tid >> 5;   // cg: 8-way c-split
    const int o = ot * 2 + ol, f0 = ft * 16;

    for (int i = tid; i < 8192; i += 256) {
        int bh = i >> 11, c = (i >> 4) & 127, ff = i & 15;
        Stile[bh][c][ff] = S[(size_t)bh * 16384 + c * 128 + f0 + ff];
    }
    __syncthreads();

    float g0 = 0.f, g1 = 0.f, g2 = 0.f, g3 = 0.f;  // gre_b0, gmi_b0, gre_b1, gmi_b1
#pragma unroll 4
    for (int c = cg * 16; c < cg * 16 + 16; ++c) {
        float wr = Wre[((size_t)(c * 128 + o)) * 128 + f0 + fl];
        float wi = Wim[((size_t)(c * 128 + o)) * 128 + f0 + fl];
        float sc0 = Stile[0][c][fl], ss0 = Stile[1][c][fl];
        float sc1 = Stile[2][c][fl], ss1 = Stile[3][c][fl];
        g0 += sc0 * wr + ss0 * wi;  g1 += ss0 * wr - sc0 * wi;
        g2 += sc1 * wr + ss1 * wi;  g3 += ss1 * wr - sc1 * wi;
    }
    __syncthreads();
    float4v* rp = (float4v*)Stile;                 // reuse LDS: 8 cg x 32 (ol,fl)
    rp[cg * 32 + ol * 16 + fl] = (float4v){g0, g1, g2, g3};
    __syncthreads();
    if (tid < 32) {
        int tol = tid >> 4, tfl = tid & 15;
        float4v r = rp[tid];
#pragma unroll
        for (int j = 1; j < 8; ++j) r += rp[j * 32 + tid];
        const float invN = 1.0f / (float)Nn;
        float gre0 = r[0] * invN, gmi0 = r[1] * invN;
        float gre1 = r[2] * invN, gmi1 = r[3] * invN;
        int oo = ot * 2 + tol;
        Gh[(0 * 128 + oo) * 128 + f0 + tfl] = pack_hi(gre0, gmi0);
        Gl[(0 * 128 + oo) * 128 + f0 + tfl] = pack_hi(resid(gre0), resid(gmi0));
        Gh[(1 * 128 + oo) * 128 + f0 + tfl] = pack_hi(gre1, gmi1);
        Gl[(1 * 128 + oo) * 128 + f0 + tfl] = pack_hi(resid(gre1), resid(gmi1));
    }
}

// ---------------- inverse evaluation + gelu: n-tile 64, explicit B-frag double-buffer.
// k = 2f+h: even k -> cos*Gre, odd k -> sin*Gmi. Output packed into hfTh/hfTl.
__global__ __launch_bounds__(256, 3) void inv_bf(const uint_t* __restrict__ Gh,
                                                 const uint_t* __restrict__ Gl,
                                                 const float* __restrict__ ptsT,
                                                 const float* __restrict__ freqs,
                                                 uint_t* __restrict__ hfTh,
                                                 uint_t* __restrict__ hfTl) {
    __shared__ __align__(16) float kxs[128], kys[128], kzs[128];
    const int nt = blockIdx.x, b = blockIdx.y;
    const int n0 = nt * 64;
    const int tid = threadIdx.x, lane = tid & 63, wave = tid >> 6;
    const int wm = wave & 1, wn = wave >> 1;       // 2 n-halves x 2 o-halves
    const int fr = lane & 15, kg = lane >> 4;

    if (tid < 128) {
        kxs[tid] = TWOPI * freqs[tid * 3 + 0];
        kys[tid] = TWOPI * freqs[tid * 3 + 1];
        kzs[tid] = TWOPI * freqs[tid * 3 + 2];
    }

    const float* pb = ptsT + ((size_t)(b * 3) << 15);
    float px[2], py[2], pz[2];
#pragma unroll
    for (int mi = 0; mi < 2; ++mi) {
        int n = n0 + wm * 32 + mi * 16 + fr;
        px[mi] = pb[n]; py[mi] = pb[(1 << 15) + n]; pz[mi] = pb[(2 << 15) + n];
    }
    __syncthreads();

    float4v acc[2][4];
#pragma unroll
    for (int mi = 0; mi < 2; ++mi)
#pragma unroll
        for (int ni = 0; ni < 4; ++ni) acc[mi][ni] = (float4v){0.f, 0.f, 0.f, 0.f};

    frag_cast bh[2][4], bl[2][4];
    // preload kt = 0 B-frags
#pragma unroll
    for (int ni = 0; ni < 4; ++ni) {
        size_t gi = ((size_t)(b * 128 + wn * 64 + ni * 16 + fr)) * 128 + kg * 4;
        bh[0][ni].s = *(const short8*)(Gh + gi);
        bl[0][ni].s = *(const short8*)(Gl + gi);
    }

#pragma unroll
    for (int kt = 0; kt < 8; ++kt) {
        const int cur = kt & 1, nxt = cur ^ 1;
        if (kt < 7) {                              // issue next-tile loads first
            const int fb2 = (kt + 1) * 16 + kg * 4;
#pragma unroll
            for (int ni = 0; ni < 4; ++ni) {
                size_t gi = ((size_t)(b * 128 + wn * 64 + ni * 16 + fr)) * 128 + fb2;
                bh[nxt][ni].s = *(const short8*)(Gh + gi);
                bl[nxt][ni].s = *(const short8*)(Gl + gi);
            }
        }
        const int fbase = kt * 16 + kg * 4;
        float4v kxv = *(const float4v*)&kxs[fbase];
        float4v kyv = *(const float4v*)&kys[fbase];
        float4v kzv = *(const float4v*)&kzs[fbase];
#pragma unroll
        for (int mi = 0; mi < 2; ++mi) {
            frag_cast ah, al;
#pragma unroll
            for (int q = 0; q < 4; ++q) {
                float ang = px[mi] * kxv[q] + py[mi] * kyv[q] + pz[mi] * kzv[q];
                float cv = __cosf(ang), sv = __sinf(ang);
                ah.u[q] = pack_hi(cv, sv);
                al.u[q] = pack_hi(resid(cv), resid(sv));
            }
#pragma unroll
            for (int ni = 0; ni < 4; ++ni) {
                acc[mi][ni] = __builtin_amdgcn_mfma_f32_16x16x32_bf16(ah.s, bh[cur][ni].s, acc[mi][ni], 0, 0, 0);
                acc[mi][ni] = __builtin_amdgcn_mfma_f32_16x16x32_bf16(ah.s, bl[cur][ni].s, acc[mi][ni], 0, 0, 0);
                acc[mi][ni] = __builtin_amdgcn_mfma_f32_16x16x32_bf16(al.s, bh[cur][ni].s, acc[mi][ni], 0, 0, 0);
            }
        }
    }

    // epilogue: gelu (tanh approx via expf) + packed bf16 hi/lo store
#pragma unroll
    for (int mi = 0; mi < 2; ++mi)
#pragma unroll
        for (int ni = 0; ni < 4; ++ni) {
            float g[4];
#pragma unroll
            for (int r = 0; r < 4; ++r) {
                float v = acc[mi][ni][r];
                float u2 = 1.5957691216057308f * (v + 0.044715f * v * v * v);
                float t = 1.0f - 2.0f / (1.0f + __expf(u2));
                g[r] = 0.5f * v * (1.0f + t);
            }
            int o = wn * 64 + ni * 16 + fr;
            int nb = n0 + wm * 32 + mi * 16 + kg * 4;
            size_t di = ((size_t)(b * 128 + o) << 14) + (nb >> 1);
            uint2v hv = { pack_hi(g[0], g[1]), pack_hi(g[2], g[3]) };
            uint2v lv = { pack_hi(resid(g[0]), resid(g[1])), pack_hi(resid(g[2]), resid(g[3])) };
            *(uint2v*)(hfTh + di) = hv;
            *(uint2v*)(hfTl + di) = lv;
        }
}

// ---------------- out projection (reads packed hfT planes)
__global__ __launch_bounds__(256) void out_proj(const uint_t* __restrict__ hfTh,
                                                const uint_t* __restrict__ hfTl,
                                                const float* __restrict__ w,
                                                const float* __restrict__ bias,
                                                float* __restrict__ u) {
    int i = blockIdx.x * 256 + threadIdx.x;        // b*(N/2) + np
    int b = i >> 14, np = i & 16383;
    const uint_t* hp = hfTh + ((size_t)(b * 128) << 14) + np;
    const uint_t* lp = hfTl + ((size_t)(b * 128) << 14) + np;
    float s0a = bias[0], s1a = bias[1], s0b = bias[0], s1b = bias[1];
#pragma unroll 4
    for (int c = 0; c < 128; ++c) {
        uint_t hv = hp[(size_t)c << 14], lv = lp[(size_t)c << 14];
        float v0 = asf(hv << 16) + asf(lv << 16);
        float v1 = asf(hv & 0xffff0000u) + asf(lv & 0xffff0000u);
        float w0 = w[c * 2 + 0], w1 = w[c * 2 + 1];
        s0a += v0 * w0; s1a += v0 * w1;
        s0b += v1 * w0; s1b += v1 * w1;
    }
    float4v o4 = {s0a, s1a, s0b, s1b};
    *(float4v*)(u + ((size_t)(b << 15) + np * 2) * 2) = o4;
}

extern "C" void kernel_launch(void* const* d_in, const int* in_sizes, int n_in,
                              void* d_out, int out_size, void* d_ws, size_t ws_size,
                              hipStream_t stream) {
    const float* a        = (const float*)d_in[0];
    const float* x        = (const float*)d_in[1];
    const float* y        = (const float*)d_in[2];
    const float* fc_in_w  = (const float*)d_in[3];
    const float* fc_in_b  = (const float*)d_in[4];
    const float* freqs    = (const float*)d_in[5];
    const float* w_real   = (const float*)d_in[6];
    const float* w_imag   = (const float*)d_in[7];
    const float* fc_out_w = (const float*)d_in[8];
    const float* fc_out_b = (const float*)d_in[9];
    float* out = (float*)d_out;

    uint_t* ws    = (uint_t*)d_ws;
    uint_t* hfTh  = ws;                                        // B*C*N/2 = 4,194,304 dwords
    uint_t* hfTl  = hfTh + (size_t)Bb * Cc * Nn / 2;           // 4,194,304
    float*  Spart = (float*)(hfTl + (size_t)Bb * Cc * Nn / 2); // B*2*SKN*PS = 8,421,376 floats
    float*  S     = Spart + (size_t)Bb * 2 * SKN * PS;         // 65,536
    uint_t* Gh    = (uint_t*)(S + (size_t)Bb * 2 * Cc * Ff);   // 32,768
    uint_t* Gl    = Gh + (size_t)Bb * Cc * Ff;                 // 32,768
    float*  xT    = (float*)(Gl + (size_t)Bb * Cc * Ff);       // 196,608 floats
    float*  yT    = xT + (size_t)Bb * 3 * Nn;                  // 196,608

    prep_xt<<<(Bb * Nn) / 256, 256, 0, stream>>>(x, y, xT, yT);
    in_proj<<<(Bb * Cc * Nn / 2) / 256, 256, 0, stream>>>(a, fc_in_w, fc_in_b, hfTh, hfTl);

    for (int l = 0; l < LL; ++l) {
        const float* k   = freqs  + (size_t)l * Ff * 3;
        const float* Wre = w_real + (size_t)l * Cc * Cc * Ff;
        const float* Wim = w_imag + (size_t)l * Cc * Cc * Ff;
        const float* pT  = (l < LL - 1) ? xT : yT;

        fwd_bf<<<dim3(SKN, 4, Bb), 256, 0, stream>>>(hfTh, hfTl, xT, k, Spart);
        reduce_kernel<<<dim3(256, 4), 256, 0, stream>>>(Spart, S);
        mix_kernel<<<dim3(64, 8), 256, 0, stream>>>(S, Wre, Wim, Gh, Gl);
        inv_bf<<<dim3(Nn / 64, Bb), 256, 0, stream>>>(Gh, Gl, pT, k, hfTh, hfTl);
    }

    out_proj<<<(Bb * Nn / 2) / 256, 256, 0, stream>>>(hfTh, hfTl, fc_out_w, fc_out_b, out);
}

// Round 8
// 411.398 us; speedup vs baseline: 1.5818x; 1.2240x over previous
//
#include <hip/hip_runtime.h>
#include <math.h>

#define Bb 2
#define Nn 32768
#define Cc 128
#define Ff 128
#define LL 4
#define SKN 128
#define PS 16448   // Spart plane stride (floats): breaks power-of-2 channel aliasing

typedef __attribute__((ext_vector_type(8))) short short8;
typedef __attribute__((ext_vector_type(4))) float float4v;
typedef __attribute__((ext_vector_type(2))) unsigned int uint2v;
typedef unsigned short ushort_t;
typedef unsigned int uint_t;

union frag_cast { short8 s; uint_t u[4]; };
union vec8 { float4v v[2]; float s[8]; };

__device__ inline uint_t asu(float f) { union { float f; uint_t u; } x; x.f = f; return x.u; }
__device__ inline float asf(uint_t u) { union { uint_t u; float f; } x; x.u = u; return x.f; }
// pack: low16 = bf16-trunc(v0), high16 = bf16-trunc(v1) -- single v_perm_b32
__device__ inline uint_t pack_hi(float v0, float v1) {
    return __builtin_amdgcn_perm(asu(v1), asu(v0), 0x07060302u);
}
// exact residual after bf16 truncation
__device__ inline float resid(float v) { return v - asf(asu(v) & 0xffff0000u); }

typedef __attribute__((address_space(1))) const uint_t guint;
typedef __attribute__((address_space(3))) uint_t luint;
__device__ inline void gload16(const uint_t* g, uint_t* l) {
    __builtin_amdgcn_global_load_lds((guint*)g, (luint*)l, 16, 0, 0);
}

// ---------------- prep: transpose x,y -> [b][d][n] planes
__global__ __launch_bounds__(256) void prep_xt(const float* __restrict__ x,
                                               const float* __restrict__ y,
                                               float* __restrict__ xT,
                                               float* __restrict__ yT) {
    int i = blockIdx.x * 256 + threadIdx.x;        // b*Nn + n
    int b = i >> 15, n = i & 32767;
    const float* xp = x + (size_t)i * 3;
    const float* yp = y + (size_t)i * 3;
    size_t base = ((size_t)(b * 3) << 15) + n;
    xT[base] = xp[0]; xT[base + (1 << 15)] = xp[1]; xT[base + (2 << 15)] = xp[2];
    yT[base] = yp[0]; yT[base + (1 << 15)] = yp[1]; yT[base + (2 << 15)] = yp[2];
}

// ---------------- in projection -> packed bf16 hi/lo planes hfTh/hfTl[b][c][n-pair]
__global__ __launch_bounds__(256) void in_proj(const float* __restrict__ a,
                                               const float* __restrict__ w,
                                               const float* __restrict__ bias,
                                               uint_t* __restrict__ hfTh,
                                               uint_t* __restrict__ hfTl) {
    int idx = blockIdx.x * 256 + threadIdx.x;      // b*C*(N/2) + c*(N/2) + np
    int np = idx & 16383;
    int c = (idx >> 14) & 127;
    int b = idx >> 21;
    int n = np * 2;
    const float* ap = a + (((size_t)(b << 15)) + n) * 4;
    float s0 = bias[c], s1 = s0;
#pragma unroll
    for (int i = 0; i < 4; ++i) { s0 += ap[i] * w[i * Cc + c]; s1 += ap[4 + i] * w[i * Cc + c]; }
    hfTh[idx] = pack_hi(s0, s1);
    hfTl[idx] = pack_hi(resid(s0), resid(s1));
}

// ---------------- forward transform: LDS double-buffer via global_load_lds (unsinkable DMA).
// Block 256 thr = 4 waves (h = wave&1, wn = wave>>1); wave tile 64c x 32f; grid (SKN, ct2*ft2, Bb).
// Spart[b,h,sk][c][f] = sum_{n in chunk} hf[b][c][n] * trig_h(2pi x[n]·k[f])
__global__ __launch_bounds__(256) void fwd_lds(const uint_t* __restrict__ hfTh,
                                               const uint_t* __restrict__ hfTl,
                                               const float* __restrict__ xT,
                                               const float* __restrict__ freqs,
                                               float* __restrict__ Spart) {
    __shared__ __align__(16) uint_t Ah_s[2][1024], Al_s[2][1024];   // 2 bufs x 64c x 16 dwords

    const int sk = blockIdx.x;
    const int ct = blockIdx.y & 1, ft = blockIdx.y >> 1;
    const int b = blockIdx.z;
    const int tid = threadIdx.x, lane = tid & 63, wave = tid >> 6;
    const int h = wave & 1, wn = wave >> 1;
    const int fr = lane & 15, kg = lane >> 4;
    const int crow0 = b * 128 + ct * 64;

    // raw per-lane frequencies (revolutions: ang/2pi = x·k)
    float kx[2], ky[2], kz[2];
#pragma unroll
    for (int ni = 0; ni < 2; ++ni) {
        int f = ft * 64 + wn * 32 + ni * 16 + fr;
        kx[ni] = freqs[f * 3 + 0];
        ky[ni] = freqs[f * 3 + 1];
        kz[ni] = freqs[f * 3 + 2];
    }

    const float* xb = xT + ((size_t)(b * 3) << 15);

    // staging address (kt-invariant part): lane -> row, 16B chunk
    const int srow = wave * 16 + (lane >> 2);
    const size_t gbase = ((size_t)(crow0 + srow) << 14) + (size_t)((lane & 3) * 4);
    const int npair0 = sk * 128;                   // dword offset of this chunk in a row

    float4v acc[4][2];
#pragma unroll
    for (int mi = 0; mi < 4; ++mi)
#pragma unroll
        for (int ni = 0; ni < 2; ++ni) acc[mi][ni] = (float4v){0.f, 0.f, 0.f, 0.f};

    vec8 X0[2], X1[2], X2[2];
    // preload: stage kt0 -> buf0, X[0]
    gload16(hfTh + gbase + npair0, &Ah_s[0][wave * 256]);
    gload16(hfTl + gbase + npair0, &Al_s[0][wave * 256]);
    {
        const int nbase = sk * 256 + kg * 8;
        X0[0].v[0] = *(const float4v*)(xb + nbase);
        X0[0].v[1] = *(const float4v*)(xb + nbase + 4);
        X1[0].v[0] = *(const float4v*)(xb + (1 << 15) + nbase);
        X1[0].v[1] = *(const float4v*)(xb + (1 << 15) + nbase + 4);
        X2[0].v[0] = *(const float4v*)(xb + (2 << 15) + nbase);
        X2[0].v[1] = *(const float4v*)(xb + (2 << 15) + nbase + 4);
    }

#pragma unroll
    for (int kt = 0; kt < 8; ++kt) {
        const int cur = kt & 1, nxt = cur ^ 1;
        __syncthreads();                           // buf cur staged; prev reads of buf nxt done
        if (kt < 7) {
            gload16(hfTh + gbase + npair0 + (kt + 1) * 16, &Ah_s[nxt][wave * 256]);
            gload16(hfTl + gbase + npair0 + (kt + 1) * 16, &Al_s[nxt][wave * 256]);
            const int nbase2 = sk * 256 + (kt + 1) * 32 + kg * 8;
            X0[nxt].v[0] = *(const float4v*)(xb + nbase2);
            X0[nxt].v[1] = *(const float4v*)(xb + nbase2 + 4);
            X1[nxt].v[0] = *(const float4v*)(xb + (1 << 15) + nbase2);
            X1[nxt].v[1] = *(const float4v*)(xb + (1 << 15) + nbase2 + 4);
            X2[nxt].v[0] = *(const float4v*)(xb + (2 << 15) + nbase2);
            X2[nxt].v[1] = *(const float4v*)(xb + (2 << 15) + nbase2 + 4);
        }
        // trig: revolutions = x·k, fract, raw v_sin/v_cos (wave-uniform h branch)
        float r[16], tv[16];
#pragma unroll
        for (int ni = 0; ni < 2; ++ni)
#pragma unroll
            for (int q = 0; q < 4; ++q) {
                float rv0 = X0[cur].s[2 * q] * kx[ni] + X1[cur].s[2 * q] * ky[ni] + X2[cur].s[2 * q] * kz[ni];
                float rv1 = X0[cur].s[2 * q + 1] * kx[ni] + X1[cur].s[2 * q + 1] * ky[ni] + X2[cur].s[2 * q + 1] * kz[ni];
                r[ni * 8 + 2 * q] = __builtin_amdgcn_fractf(rv0);
                r[ni * 8 + 2 * q + 1] = __builtin_amdgcn_fractf(rv1);
            }
        if (h) {
#pragma unroll
            for (int i = 0; i < 16; ++i) tv[i] = __builtin_amdgcn_sinf(r[i]);
        } else {
#pragma unroll
            for (int i = 0; i < 16; ++i) tv[i] = __builtin_amdgcn_cosf(r[i]);
        }
        frag_cast bh[2], bl[2];
#pragma unroll
        for (int ni = 0; ni < 2; ++ni)
#pragma unroll
            for (int q = 0; q < 4; ++q) {
                float v0 = tv[ni * 8 + 2 * q], v1 = tv[ni * 8 + 2 * q + 1];
                bh[ni].u[q] = pack_hi(v0, v1);
                bl[ni].u[q] = pack_hi(resid(v0), resid(v1));
            }
#pragma unroll
        for (int mi = 0; mi < 4; ++mi) {
            frag_cast ah, al;
            ah.s = *(const short8*)&Ah_s[cur][(mi * 16 + fr) * 16 + kg * 4];
            al.s = *(const short8*)&Al_s[cur][(mi * 16 + fr) * 16 + kg * 4];
#pragma unroll
            for (int ni = 0; ni < 2; ++ni) {
                acc[mi][ni] = __builtin_amdgcn_mfma_f32_16x16x32_bf16(ah.s, bh[ni].s, acc[mi][ni], 0, 0, 0);
                acc[mi][ni] = __builtin_amdgcn_mfma_f32_16x16x32_bf16(ah.s, bl[ni].s, acc[mi][ni], 0, 0, 0);
                acc[mi][ni] = __builtin_amdgcn_mfma_f32_16x16x32_bf16(al.s, bh[ni].s, acc[mi][ni], 0, 0, 0);
            }
        }
    }

    float* op = Spart + (size_t)((b * 2 + h) * SKN + sk) * PS;
#pragma unroll
    for (int mi = 0; mi < 4; ++mi)
#pragma unroll
        for (int ni = 0; ni < 2; ++ni)
#pragma unroll
            for (int r2 = 0; r2 < 4; ++r2) {
                int c = ct * 64 + mi * 16 + kg * 4 + r2;
                int f = ft * 64 + wn * 32 + ni * 16 + fr;
                op[c * 128 + f] = acc[mi][ni][r2];
            }
}

// ---------------- reduce split-K partials, two-stage in-block (1024 blocks)
__global__ __launch_bounds__(256) void reduce_kernel(const float* __restrict__ Spart,
                                                     float* __restrict__ S) {
    __shared__ float red[4][64];
    const int chunk = blockIdx.x, bh = blockIdx.y;
    const int tid = threadIdx.x;
    const int cfl = tid & 63, q = tid >> 6;
    const float* p = Spart + (size_t)bh * SKN * PS + (size_t)(q * 32) * PS + chunk * 64 + cfl;
    float s = 0.0f;
#pragma unroll 8
    for (int k = 0; k < 32; ++k) s += p[(size_t)k * PS];
    red[q][cfl] = s;
    __syncthreads();
    if (tid < 64) {
        float t = red[0][tid] + red[1][tid] + red[2][tid] + red[3][tid];
        S[bh * 16384 + chunk * 64 + tid] = t;
    }
}

// ---------------- channel mixing -> packed bf16 hi/lo G planes (512 blocks, W read once)
__global__ __launch_bounds__(256) void mix_kernel(const float* __restrict__ S,
                                                  const float* __restrict__ Wre,
                                                  const float* __restrict__ Wim,
                                                  uint_t* __restrict__ Gh,
                                                  uint_t* __restrict__ Gl) {
    __shared__ float Stile[4][128][16];            // [b*2+h][c][f-local], 32 KB
    const int ot = blockIdx.x;                     // 64 tiles of 2 o
    const int ft = blockIdx.y;                     // 8 tiles of 16 f
    const int tid = threadIdx.x;
    const int fl = tid & 15, ol = (tid >> 4) & 1, cg = tid >> 5;   // cg: 8-way c-split
    const int o = ot * 2 + ol, f0 = ft * 16;

    for (int i = tid; i < 8192; i += 256) {
        int bh = i >> 11, c = (i >> 4) & 127, ff = i & 15;
        Stile[bh][c][ff] = S[(size_t)bh * 16384 + c * 128 + f0 + ff];
    }
    __syncthreads();

    float g0 = 0.f, g1 = 0.f, g2 = 0.f, g3 = 0.f;  // gre_b0, gmi_b0, gre_b1, gmi_b1
#pragma unroll 4
    for (int c = cg * 16; c < cg * 16 + 16; ++c) {
        float wr = Wre[((size_t)(c * 128 + o)) * 128 + f0 + fl];
        float wi = Wim[((size_t)(c * 128 + o)) * 128 + f0 + fl];
        float sc0 = Stile[0][c][fl], ss0 = Stile[1][c][fl];
        float sc1 = Stile[2][c][fl], ss1 = Stile[3][c][fl];
        g0 += sc0 * wr + ss0 * wi;  g1 += ss0 * wr - sc0 * wi;
        g2 += sc1 * wr + ss1 * wi;  g3 += ss1 * wr - sc1 * wi;
    }
    __syncthreads();
    float4v* rp = (float4v*)Stile;                 // reuse LDS: 8 cg x 32 (ol,fl)
    rp[cg * 32 + ol * 16 + fl] = (float4v){g0, g1, g2, g3};
    __syncthreads();
    if (tid < 32) {
        int tol = tid >> 4, tfl = tid & 15;
        float4v r = rp[tid];
#pragma unroll
        for (int j = 1; j < 8; ++j) r += rp[j * 32 + tid];
        const float invN = 1.0f / (float)Nn;
        float gre0 = r[0] * invN, gmi0 = r[1] * invN;
        float gre1 = r[2] * invN, gmi1 = r[3] * invN;
        int oo = ot * 2 + tol;
        Gh[(0 * 128 + oo) * 128 + f0 + tfl] = pack_hi(gre0, gmi0);
        Gl[(0 * 128 + oo) * 128 + f0 + tfl] = pack_hi(resid(gre0), resid(gmi0));
        Gh[(1 * 128 + oo) * 128 + f0 + tfl] = pack_hi(gre1, gmi1);
        Gl[(1 * 128 + oo) * 128 + f0 + tfl] = pack_hi(resid(gre1), resid(gmi1));
    }
}

// ---------------- inverse evaluation + gelu: B (G planes) register-resident for whole block,
// stream n (4 iters x 32n). 4 waves = 4 o-quarters (ni=2). Zero in-loop loads except pts.
// k = 2f+h: even k -> cos*Gre, odd k -> sin*Gmi. Output packed into hfTh/hfTl.
__global__ __launch_bounds__(256, 2) void inv_reg(const uint_t* __restrict__ Gh,
                                                  const uint_t* __restrict__ Gl,
                                                  const float* __restrict__ ptsT,
                                                  const float* __restrict__ freqs,
                                                  uint_t* __restrict__ hfTh,
                                                  uint_t* __restrict__ hfTl) {
    __shared__ __align__(16) float kxs[128], kys[128], kzs[128];
    const int nt = blockIdx.x, b = blockIdx.y;
    const int tid = threadIdx.x, lane = tid & 63, wn = tid >> 6;
    const int fr = lane & 15, kg = lane >> 4;

    if (tid < 128) {                               // raw k (revolutions)
        kxs[tid] = freqs[tid * 3 + 0];
        kys[tid] = freqs[tid * 3 + 1];
        kzs[tid] = freqs[tid * 3 + 2];
    }
    __syncthreads();

    // B-frags: loop-invariant, live in registers for the whole kernel (128 VGPR)
    frag_cast bh[8][2], bl[8][2];
#pragma unroll
    for (int kt = 0; kt < 8; ++kt)
#pragma unroll
        for (int ni = 0; ni < 2; ++ni) {
            size_t gi = ((size_t)(b * 128 + wn * 32 + ni * 16 + fr)) * 128 + kt * 16 + kg * 4;
            bh[kt][ni].s = *(const short8*)(Gh + gi);
            bl[kt][ni].s = *(const short8*)(Gl + gi);
        }

    const float* pb = ptsT + ((size_t)(b * 3) << 15);
    const int stripe0 = nt * 128;

    for (int it = 0; it < 4; ++it) {
        const int n0 = stripe0 + it * 32;
        float px[2], py[2], pz[2];
#pragma unroll
        for (int mi = 0; mi < 2; ++mi) {
            int n = n0 + mi * 16 + fr;
            px[mi] = pb[n]; py[mi] = pb[(1 << 15) + n]; pz[mi] = pb[(2 << 15) + n];
        }
        float4v acc[2][2];
#pragma unroll
        for (int mi = 0; mi < 2; ++mi)
#pragma unroll
            for (int ni = 0; ni < 2; ++ni) acc[mi][ni] = (float4v){0.f, 0.f, 0.f, 0.f};

#pragma unroll
        for (int kt = 0; kt < 8; ++kt) {
            float4v kxv = *(const float4v*)&kxs[kt * 16 + kg * 4];
            float4v kyv = *(const float4v*)&kys[kt * 16 + kg * 4];
            float4v kzv = *(const float4v*)&kzs[kt * 16 + kg * 4];
#pragma unroll
            for (int mi = 0; mi < 2; ++mi) {
                frag_cast ah, al;
#pragma unroll
                for (int q = 0; q < 4; ++q) {
                    float rev = px[mi] * kxv[q] + py[mi] * kyv[q] + pz[mi] * kzv[q];
                    float rr = __builtin_amdgcn_fractf(rev);
                    float cv = __builtin_amdgcn_cosf(rr);
                    float sv = __builtin_amdgcn_sinf(rr);
                    ah.u[q] = pack_hi(cv, sv);
                    al.u[q] = pack_hi(resid(cv), resid(sv));
                }
#pragma unroll
                for (int ni = 0; ni < 2; ++ni) {
                    acc[mi][ni] = __builtin_amdgcn_mfma_f32_16x16x32_bf16(ah.s, bh[kt][ni].s, acc[mi][ni], 0, 0, 0);
                    acc[mi][ni] = __builtin_amdgcn_mfma_f32_16x16x32_bf16(ah.s, bl[kt][ni].s, acc[mi][ni], 0, 0, 0);
                    acc[mi][ni] = __builtin_amdgcn_mfma_f32_16x16x32_bf16(al.s, bh[kt][ni].s, acc[mi][ni], 0, 0, 0);
                }
            }
        }

        // epilogue: gelu (tanh approx via expf) + packed bf16 hi/lo store
#pragma unroll
        for (int mi = 0; mi < 2; ++mi)
#pragma unroll
            for (int ni = 0; ni < 2; ++ni) {
                float g[4];
#pragma unroll
                for (int r2 = 0; r2 < 4; ++r2) {
                    float v = acc[mi][ni][r2];
                    float u2 = 1.5957691216057308f * (v + 0.044715f * v * v * v);
                    float t = 1.0f - 2.0f / (1.0f + __expf(u2));
                    g[r2] = 0.5f * v * (1.0f + t);
                }
                int o = wn * 32 + ni * 16 + fr;
                int nb = n0 + mi * 16 + kg * 4;
                size_t di = ((size_t)(b * 128 + o) << 14) + (nb >> 1);
                uint2v hv = { pack_hi(g[0], g[1]), pack_hi(g[2], g[3]) };
                uint2v lv = { pack_hi(resid(g[0]), resid(g[1])), pack_hi(resid(g[2]), resid(g[3])) };
                *(uint2v*)(hfTh + di) = hv;
                *(uint2v*)(hfTl + di) = lv;
            }
    }
}

// ---------------- out projection (reads packed hfT planes)
__global__ __launch_bounds__(256) void out_proj(const uint_t* __restrict__ hfTh,
                                                const uint_t* __restrict__ hfTl,
                                                const float* __restrict__ w,
                                                const float* __restrict__ bias,
                                                float* __restrict__ u) {
    int i = blockIdx.x * 256 + threadIdx.x;        // b*(N/2) + np
    int b = i >> 14, np = i & 16383;
    const uint_t* hp = hfTh + ((size_t)(b * 128) << 14) + np;
    const uint_t* lp = hfTl + ((size_t)(b * 128) << 14) + np;
    float s0a = bias[0], s1a = bias[1], s0b = bias[0], s1b = bias[1];
#pragma unroll 4
    for (int c = 0; c < 128; ++c) {
        uint_t hv = hp[(size_t)c << 14], lv = lp[(size_t)c << 14];
        float v0 = asf(hv << 16) + asf(lv << 16);
        float v1 = asf(hv & 0xffff0000u) + asf(lv & 0xffff0000u);
        float w0 = w[c * 2 + 0], w1 = w[c * 2 + 1];
        s0a += v0 * w0; s1a += v0 * w1;
        s0b += v1 * w0; s1b += v1 * w1;
    }
    float4v o4 = {s0a, s1a, s0b, s1b};
    *(float4v*)(u + ((size_t)(b << 15) + np * 2) * 2) = o4;
}

extern "C" void kernel_launch(void* const* d_in, const int* in_sizes, int n_in,
                              void* d_out, int out_size, void* d_ws, size_t ws_size,
                              hipStream_t stream) {
    const float* a        = (const float*)d_in[0];
    const float* x        = (const float*)d_in[1];
    const float* y        = (const float*)d_in[2];
    const float* fc_in_w  = (const float*)d_in[3];
    const float* fc_in_b  = (const float*)d_in[4];
    const float* freqs    = (const float*)d_in[5];
    const float* w_real   = (const float*)d_in[6];
    const float* w_imag   = (const float*)d_in[7];
    const float* fc_out_w = (const float*)d_in[8];
    const float* fc_out_b = (const float*)d_in[9];
    float* out = (float*)d_out;

    uint_t* ws    = (uint_t*)d_ws;
    uint_t* hfTh  = ws;                                        // B*C*N/2 = 4,194,304 dwords
    uint_t* hfTl  = hfTh + (size_t)Bb * Cc * Nn / 2;           // 4,194,304
    float*  Spart = (float*)(hfTl + (size_t)Bb * Cc * Nn / 2); // B*2*SKN*PS = 8,421,376 floats
    float*  S     = Spart + (size_t)Bb * 2 * SKN * PS;         // 65,536
    uint_t* Gh    = (uint_t*)(S + (size_t)Bb * 2 * Cc * Ff);   // 32,768
    uint_t* Gl    = Gh + (size_t)Bb * Cc * Ff;                 // 32,768
    float*  xT    = (float*)(Gl + (size_t)Bb * Cc * Ff);       // 196,608 floats
    float*  yT    = xT + (size_t)Bb * 3 * Nn;                  // 196,608

    prep_xt<<<(Bb * Nn) / 256, 256, 0, stream>>>(x, y, xT, yT);
    in_proj<<<(Bb * Cc * Nn / 2) / 256, 256, 0, stream>>>(a, fc_in_w, fc_in_b, hfTh, hfTl);

    for (int l = 0; l < LL; ++l) {
        const float* k   = freqs  + (size_t)l * Ff * 3;
        const float* Wre = w_real + (size_t)l * Cc * Cc * Ff;
        const float* Wim = w_imag + (size_t)l * Cc * Cc * Ff;
        const float* pT  = (l < LL - 1) ? xT : yT;

        fwd_lds<<<dim3(SKN, 4, Bb), 256, 0, stream>>>(hfTh, hfTl, xT, k, Spart);
        reduce_kernel<<<dim3(256, 4), 256, 0, stream>>>(Spart, S);
        mix_kernel<<<dim3(64, 8), 256, 0, stream>>>(S, Wre, Wim, Gh, Gl);
        inv_reg<<<dim3(256, Bb), 256, 0, stream>>>(Gh, Gl, pT, k, hfTh, hfTl);
    }

    out_proj<<<(Bb * Nn / 2) / 256, 256, 0, stream>>>(hfTh, hfTl, fc_out_w, fc_out_b, out);
}